// Round 1
// baseline (159.998 us; speedup 1.0000x reference)
//
#include <hip/hip_runtime.h>
#include <hip/hip_bf16.h>

#define BQ   16
#define BK2  32     // 2B
#define SEQ  256
#define HD   768
#define NKT  12     // HD / 64 K-tiles

typedef __attribute__((ext_vector_type(8))) short bf16x8;
typedef __attribute__((ext_vector_type(4))) float f32x4;

__device__ __forceinline__ void glds16(const unsigned short* g, unsigned short* l) {
    __builtin_amdgcn_global_load_lds(
        (const __attribute__((address_space(1))) unsigned int*)g,
        (__attribute__((address_space(3))) unsigned int*)l, 16, 0, 0);
}

// branch-free RNE fp32->bf16, packed two at a time
__device__ __forceinline__ unsigned int pack2_bf16(float a, float b) {
    unsigned ua = __float_as_uint(a), ub = __float_as_uint(b);
    ua += 0x7FFFu + ((ua >> 16) & 1u);
    ub += 0x7FFFu + ((ub >> 16) & 1u);
    return (ua >> 16) | (ub & 0xFFFF0000u);
}

// ---------------- Phase 1: fp32 l2-normalize -> bf16 (+ zero d_out) --------
__global__ __launch_bounds__(256) void norm_kernel(
    const float* __restrict__ q, const float* __restrict__ k,
    unsigned short* __restrict__ qn, unsigned short* __restrict__ kn,
    float* __restrict__ out)
{
    if (blockIdx.x == 0 && threadIdx.x < 256) {      // zero 512-elem out for li's atomics
        out[threadIdx.x] = 0.f; out[threadIdx.x + 256] = 0.f;
    }
    int row  = blockIdx.x * 4 + (threadIdx.x >> 6);
    int lane = threadIdx.x & 63;
    const int NQ = BQ * SEQ;
    const float* src = (row < NQ) ? q + (size_t)row * HD
                                  : k + (size_t)(row - NQ) * HD;
    unsigned int* dst = (unsigned int*)((row < NQ) ? qn + (size_t)row * HD
                                                   : kn + (size_t)(row - NQ) * HD);
    float4 v[3];
    float ss = 0.f;
#pragma unroll
    for (int c = 0; c < 3; ++c) {
        v[c] = ((const float4*)src)[lane + 64 * c];
        ss += v[c].x * v[c].x + v[c].y * v[c].y + v[c].z * v[c].z + v[c].w * v[c].w;
    }
#pragma unroll
    for (int m = 1; m < 64; m <<= 1) ss += __shfl_xor(ss, m, 64);
    float inv = rsqrtf(fmaxf(ss, 1e-24f));
#pragma unroll
    for (int c = 0; c < 3; ++c) {
        uint2 o = make_uint2(pack2_bf16(v[c].x * inv, v[c].y * inv),
                             pack2_bf16(v[c].z * inv, v[c].w * inv));
        ((uint2*)dst)[lane + 64 * c] = o;
    }
}

// ---------------- Phase 2: block = (j, i, sh) covering 128 s x 256 t (full t)
// 8 waves as 2(s) x 4(t) of 64x64 MFMA tiles.
// Double-buffered glds staging + counted-vmcnt pipeline (T3+T4) + setprio (T5).
// Full softmax per row completes in-block; one atomicAdd per block.
__global__ __launch_bounds__(512, 2) void li_kernel(
    const unsigned short* __restrict__ qn, const unsigned short* __restrict__ kn,
    const float* __restrict__ g_ls, const float* __restrict__ g_ar,
    const int* __restrict__ q_mask, const int* __restrict__ k_mask,
    float* __restrict__ out)
{
    const int j  = blockIdx.x, i = blockIdx.y, sh = blockIdx.z;
    const int tid  = threadIdx.x;
    const int w    = tid >> 6, lane = tid & 63;
    const int ln   = lane & 15, lg = lane >> 4;
    const int wsd  = w >> 2, wt = w & 3;     // wave = (s-half, t-quarter)

    __shared__ __align__(16) unsigned short As[2 * 128 * 64];  // 32 KB, dbuf, swizzled
    __shared__ __align__(16) unsigned short Bs[2 * 256 * 64];  // 64 KB, dbuf, swizzled
    __shared__ float w2[SEQ];      // scale * exp(-alpha*d)
    __shared__ float kmB[SEQ];
    __shared__ float red[8];

    float a0 = g_ar[0];
    float alpha = (a0 > 0.f) ? a0 : 0.01f * a0;        // leaky_relu
    float scale = __expf(g_ls[0]);
    if (tid < 256) w2[tid] = scale * __expf(-alpha * (float)tid);
    else           kmB[tid - 256] = (k_mask[j * SEQ + (tid - 256)] != 0) ? 1.f : 0.f;

    // glds staging: lane covers row (base + lane>>3), swizzled source chunk.
    // LDS slot s of row r holds logical chunk s^(r&7)  (both-sides involution).
    const int rl  = lane >> 3;
    const int gch = (lane & 7) ^ rl;
    const unsigned short* aq = qn + ((size_t)i * SEQ + sh * 128 + w * 8 + rl) * HD + gch * 8;
    const unsigned short* bq = kn + ((size_t)j * SEQ + w * 8 + rl) * HD + gch * 8;
    unsigned short* alw = As + (w * 8) * 64;   // this wave's A staging base (buf 0)
    unsigned short* blw = Bs + (w * 8) * 64;   // this wave's B staging base (buf 0)

    // stage K-tile kt into buffer b: 6 glds per wave (2 A-blocks + 4 B-blocks)
#define STAGE(kt, b) do {                                            \
        const int kk_ = (kt) * 64;                                   \
        unsigned short* al_ = alw + (b) * (128 * 64);                \
        unsigned short* bl_ = blw + (b) * (256 * 64);                \
        glds16(aq + kk_,            al_);                            \
        glds16(aq + kk_ + 64 * HD,  al_ + 64 * 64);                  \
        glds16(bq + kk_,            bl_);                            \
        glds16(bq + kk_ + 64 * HD,  bl_ + 64 * 64);                  \
        glds16(bq + kk_ + 128 * HD, bl_ + 128 * 64);                 \
        glds16(bq + kk_ + 192 * HD, bl_ + 192 * 64);                 \
    } while (0)

    f32x4 acc[4][4];
    const f32x4 zero4 = {0.f, 0.f, 0.f, 0.f};
#pragma unroll
    for (int a = 0; a < 4; ++a)
#pragma unroll
        for (int b = 0; b < 4; ++b) acc[a][b] = zero4;

    // prologue: fill both buffers (12 glds in flight per wave)
    STAGE(0, 0);
    STAGE(1, 1);

    for (int kt = 0; kt < NKT; ++kt) {
        const int cur = kt & 1;
        // tile kt ready (its 6 glds are the oldest); keep tile kt+1 in flight
        if (kt == NKT - 1) asm volatile("s_waitcnt vmcnt(0)" ::: "memory");
        else               asm volatile("s_waitcnt vmcnt(6)" ::: "memory");
        __builtin_amdgcn_sched_barrier(0);
        __builtin_amdgcn_s_barrier();      // all waves' tile-kt writes visible

        const bf16x8* A8 = (const bf16x8*)(As + cur * (128 * 64));
        const bf16x8* B8 = (const bf16x8*)(Bs + cur * (256 * 64));
        bf16x8 af[2][4], bfr[2][4];
#pragma unroll
        for (int ks = 0; ks < 2; ++ks) {
            const int ch = (ks * 4 + lg) ^ (ln & 7);   // unswizzle
#pragma unroll
            for (int rm = 0; rm < 4; ++rm)
                af[ks][rm] = A8[(wsd * 64 + rm * 16 + ln) * 8 + ch];
#pragma unroll
            for (int cn = 0; cn < 4; ++cn)
                bfr[ks][cn] = B8[(wt * 64 + cn * 16 + ln) * 8 + ch];
        }

        __builtin_amdgcn_s_setprio(1);
#pragma unroll
        for (int ks = 0; ks < 2; ++ks)
#pragma unroll
            for (int rm = 0; rm < 4; ++rm)
#pragma unroll
                for (int cn = 0; cn < 4; ++cn)
                    acc[rm][cn] = __builtin_amdgcn_mfma_f32_16x16x32_bf16(
                        af[ks][rm], bfr[ks][cn], acc[rm][cn], 0, 0, 0);
        __builtin_amdgcn_s_setprio(0);

        __builtin_amdgcn_s_barrier();      // all waves done reading buf[cur]
        if (kt + 2 < NKT) STAGE(kt + 2, cur);   // 2-deep prefetch into freed buffer
    }
#undef STAGE

    // epilogue: C/D layout col=ln (t), row=lg*4+r (s)
    __syncthreads();                    // full drain; reuse As as scratch
    float* zs  = (float*)As;            // [128][4] Z partials per (srow, wt)
    float* wsc = zs + 512;              // [128][4] W partials

#pragma unroll
    for (int rm = 0; rm < 4; ++rm)
#pragma unroll
        for (int r = 0; r < 4; ++r) {
            int srow = wsd * 64 + rm * 16 + lg * 4 + r;   // s within block's 128
            int s  = sh * 128 + srow;
            float ze = 0.f, we = 0.f;
#pragma unroll
            for (int cn = 0; cn < 4; ++cn) {
                int t = wt * 64 + cn * 16 + ln;           // global t (full 256 in-block)
                float sim = acc[rm][cn][r];
                int d = s - t; d = (d < 0) ? -d : d;
                float e = kmB[t] * __expf(sim * w2[d]);
                ze += e;
                we = fmaf(e, sim, we);
            }
#pragma unroll
            for (int m = 1; m < 16; m <<= 1) {            // reduce over t-16 lanes
                ze += __shfl_xor(ze, m, 64);
                we += __shfl_xor(we, m, 64);
            }
            if (ln == 0) { zs[srow * 4 + wt] = ze; wsc[srow * 4 + wt] = we; }
        }
    __syncthreads();

    float part = 0.f;
    if (tid < 128) {
        const float4 Z4 = ((const float4*)zs)[tid];
        const float4 W4 = ((const float4*)wsc)[tid];
        float Z = Z4.x + Z4.y + Z4.z + Z4.w;
        float W = W4.x + W4.y + W4.z + W4.w;
        float pt = (Z > 0.f) ? (W / Z) : 0.f;
        part = pt * (float)q_mask[i * SEQ + sh * 128 + tid];
    }
#pragma unroll
    for (int m = 1; m < 64; m <<= 1) part += __shfl_xor(part, m, 64);
    if (lane == 0) red[w] = part;
    __syncthreads();
    if (tid == 0) {
        float tot = red[0] + red[1] + red[2] + red[3]
                  + red[4] + red[5] + red[6] + red[7];
        atomicAdd(&out[i * BK2 + j], tot);
    }
}

extern "C" void kernel_launch(void* const* d_in, const int* in_sizes, int n_in,
                              void* d_out, int out_size, void* d_ws, size_t ws_size,
                              hipStream_t stream) {
    const float* q  = (const float*)d_in[0];   // [16,256,768] f32
    const float* k  = (const float*)d_in[1];   // [32,256,768] f32
    const float* ls = (const float*)d_in[2];   // scalar
    const float* ar = (const float*)d_in[3];   // scalar
    const int* qm   = (const int*)d_in[4];     // [16,256]
    const int* km   = (const int*)d_in[5];     // [32,256]
    float* out      = (float*)d_out;           // [16,32] f32

    unsigned short* qn = (unsigned short*)d_ws;            // 16*256*768 bf16
    unsigned short* kn = qn + (size_t)BQ * SEQ * HD;       // 32*256*768 bf16

    norm_kernel<<<(BQ + BK2) * SEQ / 4, 256, 0, stream>>>(q, k, qn, kn, (float*)d_out);
    li_kernel<<<dim3(BK2, BQ, 2), 512, 0, stream>>>(qn, kn, ls, ar, qm, km, (float*)d_out);
}